// Round 17
// baseline (217.278 us; speedup 1.0000x reference)
//
#include <hip/hip_runtime.h>

// MS-SSIM, 5 levels, 16x3x512x512 fp32, scalar fp32 out.
//
// R22 = R21 resubmitted (R16-round bench died to an infra flake; kernel
// audited: no sync hazard, no OOB, LDS layout exact). R21 = R20 with L1
// moved to the PROVEN staged-LDS structure (R17's biggest tail win):
//   - l0: dual-quad h-pass + X1 store (R20: 83.4us, WRITE 25MB clean).
//   - tail (4320 blocks, deep-first): L4/L3/L2 as R17; L1 now 3072 T32
//     blocks, each stages its 42x44 X1 region into LDS (stage_copy:
//     straight v4 copy, values read ONCE, coalesced; OOB->0 == guarded
//     path) then conv-from-LDS. L1 loads 7.3M -> 2.8M v4. Tail LDS
//     union 37,296B (no T64 path) -- still 4 blocks/CU.
//   - finalize: ranges updated (accT 4320 slots).
// Bitwise: all per-output arithmetic identical; L1 partial grouping
// changes (T64->T32) -- R19 precedent kept absmax 0.0.
// Held: deep levels read X1 only (R10/R12); staged-once coalesced
// pooling (R12/R17); no per-block agent-scope fences (R11); deps at
// dispatch boundaries; no offset-pointer calls (R14); WRITE_SIZE =
// spill detector (ideal 25MB); launch_bounds(512,4) (R16).

#define NTHR 512

typedef float v4  __attribute__((ext_vector_type(4)));
typedef float v2f __attribute__((ext_vector_type(2)));

__device__ __forceinline__ float frcp(float x) { return __builtin_amdgcn_rcpf(x); }

#define GW_DEF const float GW[11] = {0.00102840f, 0.00759877f, 0.03600070f, \
    0.10936069f, 0.21300636f, 0.26601172f, 0.21300636f, 0.10936069f,        \
    0.03600070f, 0.00759877f, 0.00102840f};

__device__ __forceinline__ void conv11(const float* s, const float* d,
                                       v4& hs, v4& hd, v4& hss, v4& hdd)
{
    GW_DEF
    #pragma unroll
    for (int j = 0; j < 11; ++j) {
        float w = GW[j];
        v4 sv = {s[j], s[j+1], s[j+2], s[j+3]};
        v4 dv = {d[j], d[j+1], d[j+2], d[j+3]};
        v4 wsv = w * sv, wdv = w * dv;
        hs += wsv; hd += wdv; hss += wsv * sv; hdd += wdv * dv;
    }
}

// ---- h-pass (l0): 8-output tasks, dual-quad conv (R18/R20).
template<int TROWS>
__device__ void hpass_direct8(const float* __restrict__ p1, const float* __restrict__ p2,
                              int H, int tx0, int ty0, v4* hb)
{
    constexpr int HR = TROWS + 10;
    for (int task = threadIdx.x; task < HR * 4; task += NTHR) {
        const int r = task >> 2, cg = task & 3;
        const int gr = ty0 + r;
        const int c0 = tx0 + cg * 8;
        v4 hsA = 0.f, hdA = 0.f, hssA = 0.f, hddA = 0.f;
        v4 hsB = 0.f, hdB = 0.f, hssB = 0.f, hddB = 0.f;
        if (gr < H) {
            float s[20], d[20];
            if (c0 + 20 <= H) {
                const float* pa = p1 + (size_t)gr * H + c0;
                const float* pb = p2 + (size_t)gr * H + c0;
                v4 va0 = *(const v4*)(pa);
                v4 va1 = *(const v4*)(pa + 4);
                v4 va2 = *(const v4*)(pa + 8);
                v4 va3 = *(const v4*)(pa + 12);
                v4 va4 = *(const v4*)(pa + 16);
                v4 vb0 = *(const v4*)(pb);
                v4 vb1 = *(const v4*)(pb + 4);
                v4 vb2 = *(const v4*)(pb + 8);
                v4 vb3 = *(const v4*)(pb + 12);
                v4 vb4 = *(const v4*)(pb + 16);
                v4 sv0 = va0 + vb0, dv0 = va0 - vb0;
                v4 sv1 = va1 + vb1, dv1 = va1 - vb1;
                v4 sv2 = va2 + vb2, dv2 = va2 - vb2;
                v4 sv3 = va3 + vb3, dv3 = va3 - vb3;
                v4 sv4 = va4 + vb4, dv4 = va4 - vb4;
                s[0]=sv0.x; s[1]=sv0.y; s[2]=sv0.z; s[3]=sv0.w;
                s[4]=sv1.x; s[5]=sv1.y; s[6]=sv1.z; s[7]=sv1.w;
                s[8]=sv2.x; s[9]=sv2.y; s[10]=sv2.z; s[11]=sv2.w;
                s[12]=sv3.x; s[13]=sv3.y; s[14]=sv3.z; s[15]=sv3.w;
                s[16]=sv4.x; s[17]=sv4.y; s[18]=sv4.z; s[19]=sv4.w;
                d[0]=dv0.x; d[1]=dv0.y; d[2]=dv0.z; d[3]=dv0.w;
                d[4]=dv1.x; d[5]=dv1.y; d[6]=dv1.z; d[7]=dv1.w;
                d[8]=dv2.x; d[9]=dv2.y; d[10]=dv2.z; d[11]=dv2.w;
                d[12]=dv3.x; d[13]=dv3.y; d[14]=dv3.z; d[15]=dv3.w;
                d[16]=dv4.x; d[17]=dv4.y; d[18]=dv4.z; d[19]=dv4.w;
            } else {
                #pragma unroll
                for (int q = 0; q < 20; ++q) {
                    int cc = c0 + q;
                    float a = (cc < H) ? p1[(size_t)gr * H + cc] : 0.f;
                    float b = (cc < H) ? p2[(size_t)gr * H + cc] : 0.f;
                    s[q] = a + b; d[q] = a - b;
                }
            }
            GW_DEF
            #pragma unroll
            for (int j = 0; j < 11; ++j) {
                float w = GW[j];
                v4 svA = {s[j],   s[j+1], s[j+2], s[j+3]};
                v4 dvA = {d[j],   d[j+1], d[j+2], d[j+3]};
                v4 svB = {s[j+4], s[j+5], s[j+6], s[j+7]};
                v4 dvB = {d[j+4], d[j+5], d[j+6], d[j+7]};
                v4 wsA = w * svA, wdA = w * dvA;
                v4 wsB = w * svB, wdB = w * dvB;
                hsA += wsA; hdA += wdA; hssA += wsA * svA; hddA += wdA * dvA;
                hsB += wsB; hdB += wdB; hssB += wsB * svB; hddB += wdB * dvB;
            }
        }
        v4* row = &hb[r * 33 + cg * 8];
        row[0] = (v4){hsA.x, hdA.x, hssA.x, hddA.x};
        row[1] = (v4){hsA.y, hdA.y, hssA.y, hddA.y};
        row[2] = (v4){hsA.z, hdA.z, hssA.z, hddA.z};
        row[3] = (v4){hsA.w, hdA.w, hssA.w, hddA.w};
        row[4] = (v4){hsB.x, hdB.x, hssB.x, hddB.x};
        row[5] = (v4){hsB.y, hdB.y, hssB.y, hddB.y};
        row[6] = (v4){hsB.z, hdB.z, hssB.z, hddB.z};
        row[7] = (v4){hsB.w, hdB.w, hssB.w, hddB.w};
    }
}

// pool2 of a 4x4 src window at (4*gr, 4*cc) — verified tree.
__device__ __forceinline__ float pool2g(const float* __restrict__ sp, int SD, int gr, int cc)
{
    const float* q = sp + (size_t)(4 * gr) * SD + 4 * cc;
    v4 r0 = *(const v4*)q;
    v4 r1 = *(const v4*)(q + SD);
    v4 r2 = *(const v4*)(q + 2 * SD);
    v4 r3 = *(const v4*)(q + 3 * SD);
    float a00 = 0.25f * ((r0.x + r0.y) + (r1.x + r1.y));
    float a01 = 0.25f * ((r0.z + r0.w) + (r1.z + r1.w));
    float a10 = 0.25f * ((r2.x + r2.y) + (r3.x + r3.y));
    float a11 = 0.25f * ((r2.z + r2.w) + (r3.z + r3.w));
    return 0.25f * ((a00 + a01) + (a10 + a11));
}

// pool3 of an 8x8 src window at (8*gr, 8*cc) — verified tree.
__device__ __forceinline__ float pool3g(const float* __restrict__ sp, int SD, int gr, int cc)
{
    const float* q = sp + (size_t)(8 * gr) * SD + 8 * cc;
    float p2h[2][2];
    #pragma unroll
    for (int h = 0; h < 2; ++h) {
        const float* qq = q + (size_t)(4 * h) * SD;
        v4 A0 = *(const v4*)qq;
        v4 A1 = *(const v4*)(qq + SD);
        v4 A2 = *(const v4*)(qq + 2 * SD);
        v4 A3 = *(const v4*)(qq + 3 * SD);
        v4 B0 = *(const v4*)(qq + 4);
        v4 B1 = *(const v4*)(qq + SD + 4);
        v4 B2 = *(const v4*)(qq + 2 * SD + 4);
        v4 B3 = *(const v4*)(qq + 3 * SD + 4);
        float p00 = 0.25f * ((A0.x + A0.y) + (A1.x + A1.y));
        float p01 = 0.25f * ((A0.z + A0.w) + (A1.z + A1.w));
        float p10 = 0.25f * ((A2.x + A2.y) + (A3.x + A3.y));
        float p11 = 0.25f * ((A2.z + A2.w) + (A3.z + A3.w));
        float q00 = 0.25f * ((B0.x + B0.y) + (B1.x + B1.y));
        float q01 = 0.25f * ((B0.z + B0.w) + (B1.z + B1.w));
        float q10 = 0.25f * ((B2.x + B2.y) + (B3.x + B3.y));
        float q11 = 0.25f * ((B2.z + B2.w) + (B3.z + B3.w));
        p2h[h][0] = 0.25f * ((p00 + p01) + (p10 + p11));
        p2h[h][1] = 0.25f * ((q00 + q01) + (q10 + q11));
    }
    return 0.25f * ((p2h[0][0] + p2h[0][1]) + (p2h[1][0] + p2h[1][1]));
}

// Stage 42x44 X1 region (pitch 45) VERBATIM (L1-T32). v4 copy; tx0 and
// X1 rows are multiples of 4 -> a v4 never straddles a row end; any v4
// with cols >= H is fully OOB -> zeros (== guarded-path semantics).
__device__ void stage_copy(const float* __restrict__ s1, const float* __restrict__ s2,
                           int H, int tx0, int ty0, float* la, float* lb)
{
    for (int t = threadIdx.x; t < 2 * 42 * 11; t += NTHR) {
        int im = t >= 42 * 11; int tt = im ? t - 42 * 11 : t;
        int rr = tt / 11, k = tt % 11;
        int y = ty0 + rr, xc = tx0 + 4 * k;
        const float* sp = im ? s2 : s1;
        float* lp = im ? lb : la;
        v4 v = {0.f, 0.f, 0.f, 0.f};
        if (y < H && xc + 3 < H) v = *(const v4*)(sp + (size_t)y * H + xc);
        lp[rr * 45 + 4 * k + 0] = v.x;
        lp[rr * 45 + 4 * k + 1] = v.y;
        lp[rr * 45 + 4 * k + 2] = v.z;
        lp[rr * 45 + 4 * k + 3] = v.w;
    }
}

// Stage 42x44 region (pitch 45) of X2-LEVEL pixels = pool1(X1). R17.
__device__ void stage_x2(const float* __restrict__ s1, const float* __restrict__ s2,
                         int tx0, int ty0, float* la, float* lb)
{
    const int SD = 256, DL = 128;
    for (int t = threadIdx.x; t < 2 * 42 * 22; t += NTHR) {
        int im = t >= 42 * 22; int tt = im ? t - 42 * 22 : t;
        int rr = tt / 22, cp = tt % 22;
        int y = ty0 + rr, x = tx0 + 2 * cp;          // x even
        const float* sp = im ? s2 : s1;
        float* lp = im ? lb : la;
        float v0 = 0.f, v1 = 0.f;
        if (y < DL && x < DL) {
            const float* q0 = sp + (size_t)(2 * y) * SD + 2 * x;
            v4 r0 = *(const v4*)q0;
            v4 r1 = *(const v4*)(q0 + SD);
            v0 = 0.25f * ((r0.x + r0.y) + (r1.x + r1.y));
            v1 = 0.25f * ((r0.z + r0.w) + (r1.z + r1.w));
        }
        lp[rr * 45 + 2 * cp]     = v0;
        lp[rr * 45 + 2 * cp + 1] = v1;
    }
}

// Stage 26x44 region (pitch 45) of LEVEL pixels = pool2(X1). Proven R13.
__device__ void stage_x3(const float* __restrict__ s1, const float* __restrict__ s2,
                         int H, int tx0, int ty0, float* la, float* lb)
{
    const int SD = 4 * H;
    for (int t = threadIdx.x; t < 2 * 26 * 44; t += NTHR) {
        int im = t >= 26 * 44; int tt = im ? t - 26 * 44 : t;
        int rr = tt / 44, cc = tt % 44;
        int y = ty0 + rr, x = tx0 + cc;
        const float* sp = im ? s2 : s1;
        float* lp = im ? lb : la;
        float v = 0.f;
        if (y < H && x < H) v = pool2g(sp, SD, y, x);
        lp[rr * 45 + cc] = v;
    }
}

// Stage 26x44 region of LEVEL pixels = pool3(X1). Proven R13.
__device__ void stage_x4(const float* __restrict__ s1, const float* __restrict__ s2,
                         int H, int tx0, int ty0, float* la, float* lb)
{
    const int SD = 8 * H;
    for (int t = threadIdx.x; t < 2 * 26 * 44; t += NTHR) {
        int im = t >= 26 * 44; int tt = im ? t - 26 * 44 : t;
        int rr = tt / 44, cc = tt % 44;
        int y = ty0 + rr, x = tx0 + cc;
        const float* sp = im ? s2 : s1;
        float* lp = im ? lb : la;
        float v = 0.f;
        if (y < H && x < H) v = pool3g(sp, SD, y, x);
        lp[rr * 45 + cc] = v;
    }
}

// ---- h-pass: level pixels staged in LDS (proven; pitch 45)
template<int TROWS>
__device__ void hpass_ldsdir(const float* la, const float* lb,
                             int H, int tx0, int ty0, v4* hb)
{
    constexpr int HR = TROWS + 10;
    (void)tx0;
    for (int task = threadIdx.x; task < HR * 8; task += NTHR) {
        const int r = task >> 3, cg2 = task & 7;
        const int gr = ty0 + r;
        const int c0 = cg2 * 4;
        v4 hs = 0.f, hd = 0.f, hss = 0.f, hdd = 0.f;
        if (gr < H) {
            float s[16], d[16];
            #pragma unroll
            for (int q = 0; q < 16; ++q) {
                float pa = la[r * 45 + c0 + q];
                float pb = lb[r * 45 + c0 + q];
                s[q] = pa + pb; d[q] = pa - pb;
            }
            conv11(s, d, hs, hd, hss, hdd);
        }
        v4* row = &hb[r * 33 + cg2 * 4];
        row[0] = (v4){hs.x, hd.x, hss.x, hdd.x};
        row[1] = (v4){hs.y, hd.y, hss.y, hdd.y};
        row[2] = (v4){hs.z, hd.z, hss.z, hdd.z};
        row[3] = (v4){hs.w, hd.w, hss.w, hdd.w};
    }
}

// ---- vertical pass + ssim/cs + block reduction (proven, verbatim)
template<int TROWS>
__device__ void vpass_reduce(int H, int tx0, int ty0, const v4* hb, float* red,
                             float* __restrict__ partS, float* __restrict__ partC)
{
    constexpr int OPT = TROWS * 32 / NTHR;
    constexpr int NW  = NTHR / 64;
    GW_DEF
    const float C1 = 1e-4f, C2 = 9e-4f;
    const int tid   = threadIdx.x;
    const int outHW = H - 10;
    const int col   = tid & 31;
    const int row0  = (tid >> 5) * OPT;
    const float colm = (tx0 + col < outHW) ? 1.f : 0.f;
    v4 A[OPT];
    #pragma unroll
    for (int k = 0; k < OPT; ++k) A[k] = 0.f;

    #pragma unroll
    for (int r = 0; r < OPT + 10; ++r) {
        v4 h = hb[(row0 + r) * 33 + col];
        #pragma unroll
        for (int k = 0; k < OPT; ++k) {
            const int j = r - k;
            if (j >= 0 && j < 11) A[k] += GW[j] * h;
        }
    }

    float ssim_t = 0.f, cs_t = 0.f;
    #pragma unroll
    for (int k = 0; k < OPT; ++k) {
        float mask = colm * ((ty0 + row0 + k < outHW) ? 1.f : 0.f);
        float mu_s = A[k].x, mu_d = A[k].y;
        float P = mu_s * mu_s, Q = mu_d * mu_d;
        float U = A[k].z - P, V = A[k].w - Q;
        float v1 = 0.5f * (U - V) + C2;
        float v2 = 0.5f * (U + V) + C2;
        float n1 = 0.5f * (P - Q) + C1;
        float d1 = 0.5f * (P + Q) + C1;
        float csv = v1 * frcp(v2);
        float ssv = n1 * csv * frcp(d1);
        cs_t   += mask * csv;
        ssim_t += mask * ssv;
    }

    #pragma unroll
    for (int off = 32; off > 0; off >>= 1) {
        ssim_t += __shfl_down(ssim_t, off);
        cs_t   += __shfl_down(cs_t, off);
    }
    int wave = tid >> 6, lane = tid & 63;
    if (lane == 0) { red[wave] = ssim_t; red[NW + wave] = cs_t; }
    __syncthreads();
    if (tid == 0) {
        float s = 0.f, c = 0.f;
        #pragma unroll
        for (int w = 0; w < NW; ++w) { s += red[w]; c += red[NW + w]; }
        partS[0] = s; partC[0] = c;
    }
}

// ---- level 0: ssim0 (dual-quad h-pass) + X1 store
__global__ __launch_bounds__(NTHR, 4) void l0_kernel(
    const float* __restrict__ img1, const float* __restrict__ img2,
    float* __restrict__ x1a, float* __restrict__ x1b,
    float* __restrict__ accS, float* __restrict__ accC)
{
    __shared__ v4 hb[74 * 33];
    __shared__ float red[16];

    const int tid = threadIdx.x;
    const int nc  = blockIdx.z;
    const int tx0 = blockIdx.x * 32;
    const int ty0 = blockIdx.y * 64;
    const int H   = 512;
    const float* p1 = img1 + (size_t)nc * H * H;
    const float* p2 = img2 + (size_t)nc * H * H;

    {
        const int r = tid >> 4, c = tid & 15;          // 32 x 16
        const int iy = ty0 + 2 * r, ix = tx0 + 2 * c;
        v2f a0 = *(const v2f*)(p1 + (size_t)iy * H + ix);
        v2f a1 = *(const v2f*)(p1 + (size_t)(iy + 1) * H + ix);
        v2f b0 = *(const v2f*)(p2 + (size_t)iy * H + ix);
        v2f b1 = *(const v2f*)(p2 + (size_t)(iy + 1) * H + ix);
        size_t o = (size_t)nc * 256 * 256 + (size_t)((ty0 >> 1) + r) * 256 + ((tx0 >> 1) + c);
        x1a[o] = 0.25f * ((a0.x + a0.y) + (a1.x + a1.y));
        x1b[o] = 0.25f * ((b0.x + b0.y) + (b1.x + b1.y));
    }

    hpass_direct8<64>(p1, p2, H, tx0, ty0, hb);
    __syncthreads();
    int fb = (int)blockIdx.x + 16 * ((int)blockIdx.y + 8 * nc);
    vpass_reduce<64>(H, tx0, ty0, hb, red, accS + fb, accC + fb);
}

// ---- levels 1..4, one launch, deep-first, ALL staged-LDS from X1
//   [0,96):      L4 H=32  T16 staged pool3(X1)
//   [96,480):    L3 H=64  T16 staged pool2(X1)
//   [480,1248):  L2 H=128 T32 staged pool1(X1)
//   [1248,4320): L1 H=256 T32 staged copy(X1)
__global__ __launch_bounds__(NTHR, 4) void tail_kernel(
    const float* __restrict__ x1a, const float* __restrict__ x1b,
    float* __restrict__ accTS, float* __restrict__ accTC)
{
    __shared__ v4 smemv[2331];          // 37,296B union (T32 max: 9324 fl)
    __shared__ float red[16];
    v4* hb = smemv;

    const int b = (int)blockIdx.x;
    const size_t X1S = (size_t)256 * 256;

    if (b >= 1248) {                    // L1: T32 staged copy
        int lbk = b - 1248;
        int cx = lbk & 7, rem = lbk >> 3, cy = rem & 7, nc = rem >> 3;
        const float* p1 = x1a + (size_t)nc * X1S;
        const float* p2 = x1b + (size_t)nc * X1S;
        int tx0 = cx * 32, ty0 = cy * 32;
        float* la = (float*)smemv + 5544;   // T32 hb = 42*33 v4 = 5544 fl
        float* lb = la + 42 * 45;           // end 9324 fl (exact fit)
        stage_copy(p1, p2, 256, tx0, ty0, la, lb);
        __syncthreads();
        hpass_ldsdir<32>(la, lb, 256, tx0, ty0, hb);
        __syncthreads();
        vpass_reduce<32>(256, tx0, ty0, hb, red, accTS + b, accTC + b);
    } else if (b >= 480) {              // L2: T32 staged pool1
        int lbk = b - 480;
        int cx = lbk & 3, rem = lbk >> 2, cy = rem & 3, nc = rem >> 2;
        const float* p1 = x1a + (size_t)nc * X1S;
        const float* p2 = x1b + (size_t)nc * X1S;
        int tx0 = cx * 32, ty0 = cy * 32;
        float* la = (float*)smemv + 5544;
        float* lb = la + 42 * 45;
        stage_x2(p1, p2, tx0, ty0, la, lb);
        __syncthreads();
        hpass_ldsdir<32>(la, lb, 128, tx0, ty0, hb);
        __syncthreads();
        vpass_reduce<32>(128, tx0, ty0, hb, red, accTS + b, accTC + b);
    } else if (b >= 96) {               // L3: T16 staged pool2
        int lbk = b - 96;
        int cx = lbk & 1, rem = lbk >> 1, cy = rem & 3, nc = rem >> 2;
        const float* p1 = x1a + (size_t)nc * X1S;
        const float* p2 = x1b + (size_t)nc * X1S;
        int tx0 = cx * 32, ty0 = cy * 16;
        float* la = (float*)smemv + 3432;   // T16 hb = 26*33 v4 = 3432 fl
        float* lb = la + 26 * 45;
        stage_x3(p1, p2, 64, tx0, ty0, la, lb);
        __syncthreads();
        hpass_ldsdir<16>(la, lb, 64, tx0, ty0, hb);
        __syncthreads();
        vpass_reduce<16>(64, tx0, ty0, hb, red, accTS + b, accTC + b);
    } else {                            // L4: T16 staged pool3
        int cy = b & 1, nc = b >> 1;
        const float* p1 = x1a + (size_t)nc * X1S;
        const float* p2 = x1b + (size_t)nc * X1S;
        int tx0 = 0, ty0 = cy * 16;
        float* la = (float*)smemv + 3432;
        float* lb = la + 26 * 45;
        stage_x4(p1, p2, 32, tx0, ty0, la, lb);
        __syncthreads();
        hpass_ldsdir<16>(la, lb, 32, tx0, ty0, hb);
        __syncthreads();
        vpass_reduce<16>(32, tx0, ty0, hb, red, accTS + b, accTC + b);
    }
}

// ---- finalize: L0 acc0 [0,6144); tail: L4 [0,96) L3 [96,480)
//      L2 [480,1248) L1 [1248,4320)
__global__ void finalize_kernel(const float* __restrict__ acc0S, const float* __restrict__ acc0C,
                                const float* __restrict__ accTS, const float* __restrict__ accTC,
                                float* __restrict__ out)
{
    __shared__ float sm[10];
    __shared__ float wred[8];
    const int tid  = (int)threadIdx.x;
    const int wave = tid >> 6, lane = tid & 63;
    const int st[5] = {0, 1248, 480, 96, 0};
    const int en[5] = {6144, 4320, 1248, 480, 96};

    for (int srs = 0; srs < 10; ++srs) {
        int l = srs >> 1;
        float p = 0.f;
        if (l == 0) {
            const float* base = (srs & 1) ? acc0C : acc0S;
            for (int i = tid; i < 6144; i += NTHR) p += base[i];
        } else {
            const float* base = (srs & 1) ? accTC : accTS;
            for (int i = st[l] + tid; i < en[l]; i += NTHR) p += base[i];
        }
        #pragma unroll
        for (int o = 32; o > 0; o >>= 1) p += __shfl_down(p, o);
        if (lane == 0) wred[wave] = p;
        __syncthreads();
        if (tid == 0) {
            float t = 0.f;
            #pragma unroll
            for (int w = 0; w < 8; ++w) t += wred[w];
            sm[srs] = t;
        }
        __syncthreads();
    }

    if (tid == 0) {
        const float w[5] = {0.0448f, 0.2856f, 0.3001f, 0.2363f, 0.1333f};
        float ms[5], mc[5];
        for (int l = 0; l < 5; ++l) {
            int oh = (512 >> l) - 10;
            float cnt = 48.f * (float)oh * (float)oh;
            ms[l] = (sm[2 * l] / cnt + 1.f) * 0.5f;
            mc[l] = (sm[2 * l + 1] / cnt + 1.f) * 0.5f;
        }
        float p2 = powf(ms[4], w[4]);
        float r = 1.f;
        for (int i = 0; i < 4; ++i) r *= powf(mc[i], w[i]) * p2;
        out[0] = r;
    }
}

extern "C" void kernel_launch(void* const* d_in, const int* in_sizes, int n_in,
                              void* d_out, int out_size, void* d_ws, size_t ws_size,
                              hipStream_t stream)
{
    (void)in_sizes; (void)n_in; (void)out_size; (void)ws_size;
    const float* img1 = (const float*)d_in[0];
    const float* img2 = (const float*)d_in[1];
    float* out = (float*)d_out;
    float* ws  = (float*)d_ws;

    // workspace (floats): acc0S[6144] acc0C[6144] accTS[4320] accTC[4320]
    //                     X1a X1b
    float* acc0S = ws;
    float* acc0C = acc0S + 6144;
    float* accTS = acc0C + 6144;
    float* accTC = accTS + 4320;
    float* x1a   = accTC + 4320;        // 20928 floats, 16B aligned
    float* x1b   = x1a + (size_t)48 * 256 * 256;

    l0_kernel<<<dim3(16, 8, 48), NTHR, 0, stream>>>(
        img1, img2, x1a, x1b, acc0S, acc0C);
    tail_kernel<<<dim3(4320), NTHR, 0, stream>>>(
        x1a, x1b, accTS, accTC);
    finalize_kernel<<<1, NTHR, 0, stream>>>(
        acc0S, acc0C, accTS, accTC, out);
}

// Round 18
// 212.223 us; speedup vs baseline: 1.0238x; 1.0238x over previous
//
#include <hip/hip_runtime.h>

// MS-SSIM, 5 levels, 16x3x512x512 fp32, scalar fp32 out.
//
// R23 (final) = component-wise best measured configuration:
//   - l0: dual-quad 8-output h-pass + X1 store (83.4us, WRITE 25MB clean,
//     consistently fastest l0 variant across R18/R20/R22 runs).
//   - tail: R17's proven mix -- L1 T64 direct on X1 (4-col burst; staged
//     variant measured neutral-to-worse in R22), L2/L3/L4 staged-LDS.
//   - finalize: proven.
// Plateau evidence: R17/R20/R22 = 213.95/215.05/217.28 (noise +-3us).
// Structural levers exhausted: cooperative fusion hangs (R6); per-block
// agent-scope finalize 10x catastrophic (R11); level-merge into critical
// dispatch regresses (R12/R19); all staging/ILP variants measured.
// Both kernels ~49% VALUBusy / 18% HBM -- latency-bound, no saturable
// pipe; ~40us inter-dispatch gaps irreducible at 3 dispatches.
// Held: deep levels read X1 only (R10/R12); pooled values staged once,
// coalesced (R12/R17); no per-block agent-scope fences (R11); deps at
// dispatch boundaries; no offset-pointer calls (R14); WRITE_SIZE =
// spill detector (ideal 25MB); launch_bounds(512,4) (R16).

#define NTHR 512

typedef float v4  __attribute__((ext_vector_type(4)));
typedef float v2f __attribute__((ext_vector_type(2)));

__device__ __forceinline__ float frcp(float x) { return __builtin_amdgcn_rcpf(x); }

#define GW_DEF const float GW[11] = {0.00102840f, 0.00759877f, 0.03600070f, \
    0.10936069f, 0.21300636f, 0.26601172f, 0.21300636f, 0.10936069f,        \
    0.03600070f, 0.00759877f, 0.00102840f};

__device__ __forceinline__ void conv11(const float* s, const float* d,
                                       v4& hs, v4& hd, v4& hss, v4& hdd)
{
    GW_DEF
    #pragma unroll
    for (int j = 0; j < 11; ++j) {
        float w = GW[j];
        v4 sv = {s[j], s[j+1], s[j+2], s[j+3]};
        v4 dv = {d[j], d[j+1], d[j+2], d[j+3]};
        v4 wsv = w * sv, wdv = w * dv;
        hs += wsv; hd += wdv; hss += wsv * sv; hdd += wdv * dv;
    }
}

// ---- h-pass variant A (l0): 8-output tasks, dual-quad conv (R18).
template<int TROWS>
__device__ void hpass_direct8(const float* __restrict__ p1, const float* __restrict__ p2,
                              int H, int tx0, int ty0, v4* hb)
{
    constexpr int HR = TROWS + 10;
    for (int task = threadIdx.x; task < HR * 4; task += NTHR) {
        const int r = task >> 2, cg = task & 3;
        const int gr = ty0 + r;
        const int c0 = tx0 + cg * 8;
        v4 hsA = 0.f, hdA = 0.f, hssA = 0.f, hddA = 0.f;
        v4 hsB = 0.f, hdB = 0.f, hssB = 0.f, hddB = 0.f;
        if (gr < H) {
            float s[20], d[20];
            if (c0 + 20 <= H) {
                const float* pa = p1 + (size_t)gr * H + c0;
                const float* pb = p2 + (size_t)gr * H + c0;
                v4 va0 = *(const v4*)(pa);
                v4 va1 = *(const v4*)(pa + 4);
                v4 va2 = *(const v4*)(pa + 8);
                v4 va3 = *(const v4*)(pa + 12);
                v4 va4 = *(const v4*)(pa + 16);
                v4 vb0 = *(const v4*)(pb);
                v4 vb1 = *(const v4*)(pb + 4);
                v4 vb2 = *(const v4*)(pb + 8);
                v4 vb3 = *(const v4*)(pb + 12);
                v4 vb4 = *(const v4*)(pb + 16);
                v4 sv0 = va0 + vb0, dv0 = va0 - vb0;
                v4 sv1 = va1 + vb1, dv1 = va1 - vb1;
                v4 sv2 = va2 + vb2, dv2 = va2 - vb2;
                v4 sv3 = va3 + vb3, dv3 = va3 - vb3;
                v4 sv4 = va4 + vb4, dv4 = va4 - vb4;
                s[0]=sv0.x; s[1]=sv0.y; s[2]=sv0.z; s[3]=sv0.w;
                s[4]=sv1.x; s[5]=sv1.y; s[6]=sv1.z; s[7]=sv1.w;
                s[8]=sv2.x; s[9]=sv2.y; s[10]=sv2.z; s[11]=sv2.w;
                s[12]=sv3.x; s[13]=sv3.y; s[14]=sv3.z; s[15]=sv3.w;
                s[16]=sv4.x; s[17]=sv4.y; s[18]=sv4.z; s[19]=sv4.w;
                d[0]=dv0.x; d[1]=dv0.y; d[2]=dv0.z; d[3]=dv0.w;
                d[4]=dv1.x; d[5]=dv1.y; d[6]=dv1.z; d[7]=dv1.w;
                d[8]=dv2.x; d[9]=dv2.y; d[10]=dv2.z; d[11]=dv2.w;
                d[12]=dv3.x; d[13]=dv3.y; d[14]=dv3.z; d[15]=dv3.w;
                d[16]=dv4.x; d[17]=dv4.y; d[18]=dv4.z; d[19]=dv4.w;
            } else {
                #pragma unroll
                for (int q = 0; q < 20; ++q) {
                    int cc = c0 + q;
                    float a = (cc < H) ? p1[(size_t)gr * H + cc] : 0.f;
                    float b = (cc < H) ? p2[(size_t)gr * H + cc] : 0.f;
                    s[q] = a + b; d[q] = a - b;
                }
            }
            GW_DEF
            #pragma unroll
            for (int j = 0; j < 11; ++j) {
                float w = GW[j];
                v4 svA = {s[j],   s[j+1], s[j+2], s[j+3]};
                v4 dvA = {d[j],   d[j+1], d[j+2], d[j+3]};
                v4 svB = {s[j+4], s[j+5], s[j+6], s[j+7]};
                v4 dvB = {d[j+4], d[j+5], d[j+6], d[j+7]};
                v4 wsA = w * svA, wdA = w * dvA;
                v4 wsB = w * svB, wdB = w * dvB;
                hsA += wsA; hdA += wdA; hssA += wsA * svA; hddA += wdA * dvA;
                hsB += wsB; hdB += wdB; hssB += wsB * svB; hddB += wdB * dvB;
            }
        }
        v4* row = &hb[r * 33 + cg * 8];
        row[0] = (v4){hsA.x, hdA.x, hssA.x, hddA.x};
        row[1] = (v4){hsA.y, hdA.y, hssA.y, hddA.y};
        row[2] = (v4){hsA.z, hdA.z, hssA.z, hddA.z};
        row[3] = (v4){hsA.w, hdA.w, hssA.w, hddA.w};
        row[4] = (v4){hsB.x, hdB.x, hssB.x, hddB.x};
        row[5] = (v4){hsB.y, hdB.y, hssB.y, hddB.y};
        row[6] = (v4){hsB.z, hdB.z, hssB.z, hddB.z};
        row[7] = (v4){hsB.w, hdB.w, hssB.w, hddB.w};
    }
}

// ---- h-pass variant B (tail L1): 4-col tasks, 8-load burst (R16/R17).
template<int TROWS>
__device__ void hpass_direct4(const float* __restrict__ p1, const float* __restrict__ p2,
                              int H, int tx0, int ty0, v4* hb)
{
    constexpr int HR = TROWS + 10;
    for (int task = threadIdx.x; task < HR * 8; task += NTHR) {
        const int r = task >> 3, cg2 = task & 7;
        const int gr = ty0 + r;
        const int c0 = tx0 + cg2 * 4;
        v4 hs = 0.f, hd = 0.f, hss = 0.f, hdd = 0.f;
        if (gr < H) {
            float s[16], d[16];
            if (c0 + 16 <= H) {
                const float* pa = p1 + (size_t)gr * H + c0;
                const float* pb = p2 + (size_t)gr * H + c0;
                v4 va0 = *(const v4*)(pa);
                v4 va1 = *(const v4*)(pa + 4);
                v4 va2 = *(const v4*)(pa + 8);
                v4 va3 = *(const v4*)(pa + 12);
                v4 vb0 = *(const v4*)(pb);
                v4 vb1 = *(const v4*)(pb + 4);
                v4 vb2 = *(const v4*)(pb + 8);
                v4 vb3 = *(const v4*)(pb + 12);
                v4 sv0 = va0 + vb0, dv0 = va0 - vb0;
                v4 sv1 = va1 + vb1, dv1 = va1 - vb1;
                v4 sv2 = va2 + vb2, dv2 = va2 - vb2;
                v4 sv3 = va3 + vb3, dv3 = va3 - vb3;
                s[0]=sv0.x; s[1]=sv0.y; s[2]=sv0.z; s[3]=sv0.w;
                s[4]=sv1.x; s[5]=sv1.y; s[6]=sv1.z; s[7]=sv1.w;
                s[8]=sv2.x; s[9]=sv2.y; s[10]=sv2.z; s[11]=sv2.w;
                s[12]=sv3.x; s[13]=sv3.y; s[14]=sv3.z; s[15]=sv3.w;
                d[0]=dv0.x; d[1]=dv0.y; d[2]=dv0.z; d[3]=dv0.w;
                d[4]=dv1.x; d[5]=dv1.y; d[6]=dv1.z; d[7]=dv1.w;
                d[8]=dv2.x; d[9]=dv2.y; d[10]=dv2.z; d[11]=dv2.w;
                d[12]=dv3.x; d[13]=dv3.y; d[14]=dv3.z; d[15]=dv3.w;
            } else {
                #pragma unroll
                for (int q = 0; q < 16; ++q) {
                    int cc = c0 + q;
                    float a = (cc < H) ? p1[(size_t)gr * H + cc] : 0.f;
                    float b = (cc < H) ? p2[(size_t)gr * H + cc] : 0.f;
                    s[q] = a + b; d[q] = a - b;
                }
            }
            conv11(s, d, hs, hd, hss, hdd);
        }
        v4* row = &hb[r * 33 + cg2 * 4];
        row[0] = (v4){hs.x, hd.x, hss.x, hdd.x};
        row[1] = (v4){hs.y, hd.y, hss.y, hdd.y};
        row[2] = (v4){hs.z, hd.z, hss.z, hdd.z};
        row[3] = (v4){hs.w, hd.w, hss.w, hdd.w};
    }
}

// pool2 of a 4x4 src window at (4*gr, 4*cc) — verified tree.
__device__ __forceinline__ float pool2g(const float* __restrict__ sp, int SD, int gr, int cc)
{
    const float* q = sp + (size_t)(4 * gr) * SD + 4 * cc;
    v4 r0 = *(const v4*)q;
    v4 r1 = *(const v4*)(q + SD);
    v4 r2 = *(const v4*)(q + 2 * SD);
    v4 r3 = *(const v4*)(q + 3 * SD);
    float a00 = 0.25f * ((r0.x + r0.y) + (r1.x + r1.y));
    float a01 = 0.25f * ((r0.z + r0.w) + (r1.z + r1.w));
    float a10 = 0.25f * ((r2.x + r2.y) + (r3.x + r3.y));
    float a11 = 0.25f * ((r2.z + r2.w) + (r3.z + r3.w));
    return 0.25f * ((a00 + a01) + (a10 + a11));
}

// pool3 of an 8x8 src window at (8*gr, 8*cc) — verified tree.
__device__ __forceinline__ float pool3g(const float* __restrict__ sp, int SD, int gr, int cc)
{
    const float* q = sp + (size_t)(8 * gr) * SD + 8 * cc;
    float p2h[2][2];
    #pragma unroll
    for (int h = 0; h < 2; ++h) {
        const float* qq = q + (size_t)(4 * h) * SD;
        v4 A0 = *(const v4*)qq;
        v4 A1 = *(const v4*)(qq + SD);
        v4 A2 = *(const v4*)(qq + 2 * SD);
        v4 A3 = *(const v4*)(qq + 3 * SD);
        v4 B0 = *(const v4*)(qq + 4);
        v4 B1 = *(const v4*)(qq + SD + 4);
        v4 B2 = *(const v4*)(qq + 2 * SD + 4);
        v4 B3 = *(const v4*)(qq + 3 * SD + 4);
        float p00 = 0.25f * ((A0.x + A0.y) + (A1.x + A1.y));
        float p01 = 0.25f * ((A0.z + A0.w) + (A1.z + A1.w));
        float p10 = 0.25f * ((A2.x + A2.y) + (A3.x + A3.y));
        float p11 = 0.25f * ((A2.z + A2.w) + (A3.z + A3.w));
        float q00 = 0.25f * ((B0.x + B0.y) + (B1.x + B1.y));
        float q01 = 0.25f * ((B0.z + B0.w) + (B1.z + B1.w));
        float q10 = 0.25f * ((B2.x + B2.y) + (B3.x + B3.y));
        float q11 = 0.25f * ((B2.z + B2.w) + (B3.z + B3.w));
        p2h[h][0] = 0.25f * ((p00 + p01) + (p10 + p11));
        p2h[h][1] = 0.25f * ((q00 + q01) + (q10 + q11));
    }
    return 0.25f * ((p2h[0][0] + p2h[0][1]) + (p2h[1][0] + p2h[1][1]));
}

// Stage 42x44 region (pitch 45) of X2-LEVEL pixels = pool1(X1). R17.
__device__ void stage_x2(const float* __restrict__ s1, const float* __restrict__ s2,
                         int tx0, int ty0, float* la, float* lb)
{
    const int SD = 256, DL = 128;
    for (int t = threadIdx.x; t < 2 * 42 * 22; t += NTHR) {
        int im = t >= 42 * 22; int tt = im ? t - 42 * 22 : t;
        int rr = tt / 22, cp = tt % 22;
        int y = ty0 + rr, x = tx0 + 2 * cp;          // x even
        const float* sp = im ? s2 : s1;
        float* lp = im ? lb : la;
        float v0 = 0.f, v1 = 0.f;
        if (y < DL && x < DL) {
            const float* q0 = sp + (size_t)(2 * y) * SD + 2 * x;
            v4 r0 = *(const v4*)q0;
            v4 r1 = *(const v4*)(q0 + SD);
            v0 = 0.25f * ((r0.x + r0.y) + (r1.x + r1.y));
            v1 = 0.25f * ((r0.z + r0.w) + (r1.z + r1.w));
        }
        lp[rr * 45 + 2 * cp]     = v0;
        lp[rr * 45 + 2 * cp + 1] = v1;
    }
}

// Stage 26x44 region (pitch 45) of LEVEL pixels = pool2(X1). Proven R13.
__device__ void stage_x3(const float* __restrict__ s1, const float* __restrict__ s2,
                         int H, int tx0, int ty0, float* la, float* lb)
{
    const int SD = 4 * H;
    for (int t = threadIdx.x; t < 2 * 26 * 44; t += NTHR) {
        int im = t >= 26 * 44; int tt = im ? t - 26 * 44 : t;
        int rr = tt / 44, cc = tt % 44;
        int y = ty0 + rr, x = tx0 + cc;
        const float* sp = im ? s2 : s1;
        float* lp = im ? lb : la;
        float v = 0.f;
        if (y < H && x < H) v = pool2g(sp, SD, y, x);
        lp[rr * 45 + cc] = v;
    }
}

// Stage 26x44 region of LEVEL pixels = pool3(X1). Proven R13.
__device__ void stage_x4(const float* __restrict__ s1, const float* __restrict__ s2,
                         int H, int tx0, int ty0, float* la, float* lb)
{
    const int SD = 8 * H;
    for (int t = threadIdx.x; t < 2 * 26 * 44; t += NTHR) {
        int im = t >= 26 * 44; int tt = im ? t - 26 * 44 : t;
        int rr = tt / 44, cc = tt % 44;
        int y = ty0 + rr, x = tx0 + cc;
        const float* sp = im ? s2 : s1;
        float* lp = im ? lb : la;
        float v = 0.f;
        if (y < H && x < H) v = pool3g(sp, SD, y, x);
        lp[rr * 45 + cc] = v;
    }
}

// ---- h-pass: level pixels staged in LDS (proven R13/R17; pitch 45)
template<int TROWS>
__device__ void hpass_ldsdir(const float* la, const float* lb,
                             int H, int tx0, int ty0, v4* hb)
{
    constexpr int HR = TROWS + 10;
    (void)tx0;
    for (int task = threadIdx.x; task < HR * 8; task += NTHR) {
        const int r = task >> 3, cg2 = task & 7;
        const int gr = ty0 + r;
        const int c0 = cg2 * 4;
        v4 hs = 0.f, hd = 0.f, hss = 0.f, hdd = 0.f;
        if (gr < H) {
            float s[16], d[16];
            #pragma unroll
            for (int q = 0; q < 16; ++q) {
                float pa = la[r * 45 + c0 + q];
                float pb = lb[r * 45 + c0 + q];
                s[q] = pa + pb; d[q] = pa - pb;
            }
            conv11(s, d, hs, hd, hss, hdd);
        }
        v4* row = &hb[r * 33 + cg2 * 4];
        row[0] = (v4){hs.x, hd.x, hss.x, hdd.x};
        row[1] = (v4){hs.y, hd.y, hss.y, hdd.y};
        row[2] = (v4){hs.z, hd.z, hss.z, hdd.z};
        row[3] = (v4){hs.w, hd.w, hss.w, hdd.w};
    }
}

// ---- vertical pass + ssim/cs + block reduction (proven, verbatim)
template<int TROWS>
__device__ void vpass_reduce(int H, int tx0, int ty0, const v4* hb, float* red,
                             float* __restrict__ partS, float* __restrict__ partC)
{
    constexpr int OPT = TROWS * 32 / NTHR;
    constexpr int NW  = NTHR / 64;
    GW_DEF
    const float C1 = 1e-4f, C2 = 9e-4f;
    const int tid   = threadIdx.x;
    const int outHW = H - 10;
    const int col   = tid & 31;
    const int row0  = (tid >> 5) * OPT;
    const float colm = (tx0 + col < outHW) ? 1.f : 0.f;
    v4 A[OPT];
    #pragma unroll
    for (int k = 0; k < OPT; ++k) A[k] = 0.f;

    #pragma unroll
    for (int r = 0; r < OPT + 10; ++r) {
        v4 h = hb[(row0 + r) * 33 + col];
        #pragma unroll
        for (int k = 0; k < OPT; ++k) {
            const int j = r - k;
            if (j >= 0 && j < 11) A[k] += GW[j] * h;
        }
    }

    float ssim_t = 0.f, cs_t = 0.f;
    #pragma unroll
    for (int k = 0; k < OPT; ++k) {
        float mask = colm * ((ty0 + row0 + k < outHW) ? 1.f : 0.f);
        float mu_s = A[k].x, mu_d = A[k].y;
        float P = mu_s * mu_s, Q = mu_d * mu_d;
        float U = A[k].z - P, V = A[k].w - Q;
        float v1 = 0.5f * (U - V) + C2;
        float v2 = 0.5f * (U + V) + C2;
        float n1 = 0.5f * (P - Q) + C1;
        float d1 = 0.5f * (P + Q) + C1;
        float csv = v1 * frcp(v2);
        float ssv = n1 * csv * frcp(d1);
        cs_t   += mask * csv;
        ssim_t += mask * ssv;
    }

    #pragma unroll
    for (int off = 32; off > 0; off >>= 1) {
        ssim_t += __shfl_down(ssim_t, off);
        cs_t   += __shfl_down(cs_t, off);
    }
    int wave = tid >> 6, lane = tid & 63;
    if (lane == 0) { red[wave] = ssim_t; red[NW + wave] = cs_t; }
    __syncthreads();
    if (tid == 0) {
        float s = 0.f, c = 0.f;
        #pragma unroll
        for (int w = 0; w < NW; ++w) { s += red[w]; c += red[NW + w]; }
        partS[0] = s; partC[0] = c;
    }
}

// ---- level 0: ssim0 (dual-quad h-pass) + X1 store
__global__ __launch_bounds__(NTHR, 4) void l0_kernel(
    const float* __restrict__ img1, const float* __restrict__ img2,
    float* __restrict__ x1a, float* __restrict__ x1b,
    float* __restrict__ accS, float* __restrict__ accC)
{
    __shared__ v4 hb[74 * 33];
    __shared__ float red[16];

    const int tid = threadIdx.x;
    const int nc  = blockIdx.z;
    const int tx0 = blockIdx.x * 32;
    const int ty0 = blockIdx.y * 64;
    const int H   = 512;
    const float* p1 = img1 + (size_t)nc * H * H;
    const float* p2 = img2 + (size_t)nc * H * H;

    {
        const int r = tid >> 4, c = tid & 15;          // 32 x 16
        const int iy = ty0 + 2 * r, ix = tx0 + 2 * c;
        v2f a0 = *(const v2f*)(p1 + (size_t)iy * H + ix);
        v2f a1 = *(const v2f*)(p1 + (size_t)(iy + 1) * H + ix);
        v2f b0 = *(const v2f*)(p2 + (size_t)iy * H + ix);
        v2f b1 = *(const v2f*)(p2 + (size_t)(iy + 1) * H + ix);
        size_t o = (size_t)nc * 256 * 256 + (size_t)((ty0 >> 1) + r) * 256 + ((tx0 >> 1) + c);
        x1a[o] = 0.25f * ((a0.x + a0.y) + (a1.x + a1.y));
        x1b[o] = 0.25f * ((b0.x + b0.y) + (b1.x + b1.y));
    }

    hpass_direct8<64>(p1, p2, H, tx0, ty0, hb);
    __syncthreads();
    int fb = (int)blockIdx.x + 16 * ((int)blockIdx.y + 8 * nc);
    vpass_reduce<64>(H, tx0, ty0, hb, red, accS + fb, accC + fb);
}

// ---- levels 1..4 in one launch, deep-first, all from X1 (R17 verbatim)
//   [0,96):      L4 H=32  T16 staged pool3(X1) -> LDS -> conv
//   [96,480):    L3 H=64  T16 staged pool2(X1) -> LDS -> conv
//   [480,1248):  L2 H=128 T32 staged pool1(X1) -> LDS -> conv
//   [1248,2784): L1 H=256 T64 direct on X1 (4-col burst h-pass)
__global__ __launch_bounds__(NTHR, 4) void tail_kernel(
    const float* __restrict__ x1a, const float* __restrict__ x1b,
    float* __restrict__ accTS, float* __restrict__ accTC)
{
    __shared__ v4 hb[74 * 33];          // 39,072B union
    __shared__ float red[16];

    const int b = (int)blockIdx.x;
    const size_t X1S = (size_t)256 * 256;

    if (b >= 1248) {                    // L1
        int lbk = b - 1248;
        int cx = lbk & 7, rem = lbk >> 3, cy = rem & 3, nc = rem >> 2;
        const float* p1 = x1a + (size_t)nc * X1S;
        const float* p2 = x1b + (size_t)nc * X1S;
        int tx0 = cx * 32, ty0 = cy * 64;
        hpass_direct4<64>(p1, p2, 256, tx0, ty0, hb);
        __syncthreads();
        vpass_reduce<64>(256, tx0, ty0, hb, red, accTS + b, accTC + b);
    } else if (b >= 480) {              // L2 (staged)
        int lbk = b - 480;
        int cx = lbk & 3, rem = lbk >> 2, cy = rem & 3, nc = rem >> 2;
        const float* p1 = x1a + (size_t)nc * X1S;
        const float* p2 = x1b + (size_t)nc * X1S;
        int tx0 = cx * 32, ty0 = cy * 32;
        float* la = (float*)hb + 5544;  // T32 hb = 42*33 v4 = 5544 fl
        float* lb = la + 42 * 45;       // end 9324 < 9768 fl
        stage_x2(p1, p2, tx0, ty0, la, lb);
        __syncthreads();
        hpass_ldsdir<32>(la, lb, 128, tx0, ty0, hb);
        __syncthreads();
        vpass_reduce<32>(128, tx0, ty0, hb, red, accTS + b, accTC + b);
    } else if (b >= 96) {               // L3
        int lbk = b - 96;
        int cx = lbk & 1, rem = lbk >> 1, cy = rem & 3, nc = rem >> 2;
        const float* p1 = x1a + (size_t)nc * X1S;
        const float* p2 = x1b + (size_t)nc * X1S;
        int tx0 = cx * 32, ty0 = cy * 16;
        float* la = (float*)hb + 3432;  // T16 hb = 26*33 v4 = 3432 fl
        float* lb = la + 26 * 45;
        stage_x3(p1, p2, 64, tx0, ty0, la, lb);
        __syncthreads();
        hpass_ldsdir<16>(la, lb, 64, tx0, ty0, hb);
        __syncthreads();
        vpass_reduce<16>(64, tx0, ty0, hb, red, accTS + b, accTC + b);
    } else {                            // L4
        int cy = b & 1, nc = b >> 1;
        const float* p1 = x1a + (size_t)nc * X1S;
        const float* p2 = x1b + (size_t)nc * X1S;
        int tx0 = 0, ty0 = cy * 16;
        float* la = (float*)hb + 3432;
        float* lb = la + 26 * 45;
        stage_x4(p1, p2, 32, tx0, ty0, la, lb);
        __syncthreads();
        hpass_ldsdir<16>(la, lb, 32, tx0, ty0, hb);
        __syncthreads();
        vpass_reduce<16>(32, tx0, ty0, hb, red, accTS + b, accTC + b);
    }
}

// ---- finalize (proven, verbatim)
__global__ void finalize_kernel(const float* __restrict__ acc0S, const float* __restrict__ acc0C,
                                const float* __restrict__ accTS, const float* __restrict__ accTC,
                                float* __restrict__ out)
{
    __shared__ float sm[10];
    __shared__ float wred[8];
    const int tid  = (int)threadIdx.x;
    const int wave = tid >> 6, lane = tid & 63;
    const int st[5] = {0, 1248, 480, 96, 0};
    const int en[5] = {6144, 2784, 1248, 480, 96};

    for (int srs = 0; srs < 10; ++srs) {
        int l = srs >> 1;
        float p = 0.f;
        if (l == 0) {
            const float* base = (srs & 1) ? acc0C : acc0S;
            for (int i = tid; i < 6144; i += NTHR) p += base[i];
        } else {
            const float* base = (srs & 1) ? accTC : accTS;
            for (int i = st[l] + tid; i < en[l]; i += NTHR) p += base[i];
        }
        #pragma unroll
        for (int o = 32; o > 0; o >>= 1) p += __shfl_down(p, o);
        if (lane == 0) wred[wave] = p;
        __syncthreads();
        if (tid == 0) {
            float t = 0.f;
            #pragma unroll
            for (int w = 0; w < 8; ++w) t += wred[w];
            sm[srs] = t;
        }
        __syncthreads();
    }

    if (tid == 0) {
        const float w[5] = {0.0448f, 0.2856f, 0.3001f, 0.2363f, 0.1333f};
        float ms[5], mc[5];
        for (int l = 0; l < 5; ++l) {
            int oh = (512 >> l) - 10;
            float cnt = 48.f * (float)oh * (float)oh;
            ms[l] = (sm[2 * l] / cnt + 1.f) * 0.5f;
            mc[l] = (sm[2 * l + 1] / cnt + 1.f) * 0.5f;
        }
        float p2 = powf(ms[4], w[4]);
        float r = 1.f;
        for (int i = 0; i < 4; ++i) r *= powf(mc[i], w[i]) * p2;
        out[0] = r;
    }
}

extern "C" void kernel_launch(void* const* d_in, const int* in_sizes, int n_in,
                              void* d_out, int out_size, void* d_ws, size_t ws_size,
                              hipStream_t stream)
{
    (void)in_sizes; (void)n_in; (void)out_size; (void)ws_size;
    const float* img1 = (const float*)d_in[0];
    const float* img2 = (const float*)d_in[1];
    float* out = (float*)d_out;
    float* ws  = (float*)d_ws;

    // workspace (floats): acc0S[6144] acc0C[6144] accTS[2784] accTC[2784]
    //                     X1a X1b
    float* acc0S = ws;
    float* acc0C = acc0S + 6144;
    float* accTS = acc0C + 6144;
    float* accTC = accTS + 2784;
    float* x1a   = accTC + 2784;
    float* x1b   = x1a + (size_t)48 * 256 * 256;

    l0_kernel<<<dim3(16, 8, 48), NTHR, 0, stream>>>(
        img1, img2, x1a, x1b, acc0S, acc0C);
    tail_kernel<<<dim3(2784), NTHR, 0, stream>>>(
        x1a, x1b, accTS, accTC);
    finalize_kernel<<<1, NTHR, 0, stream>>>(
        acc0S, acc0C, accTS, accTC, out);
}